// Round 3
// baseline (163.814 us; speedup 1.0000x reference)
//
#include <hip/hip_runtime.h>
#include <hip/hip_bf16.h>

// Problem constants (from reference):
//   B=64, C=128, 16x16 image -> 256 points per batch
//   MAP_SIZE=32 (1024 BEV cells), CELL=0.1f, CAM_HEIGHT=1.72f, HMAX=14
// Inputs float32, output float32 (reference dtypes).
#define NBATCH   64
#define NCHAN    128
#define NPTS     256
#define MAPS     32
#define NCELL    (MAPS * MAPS)   // 1024
#define HMAXV    14
#define CELLF    0.1f            // float32(3.2/32)
#define CAMH     1.72f

__global__ __launch_bounds__(256) void voxel_bev_kernel(
    const float* __restrict__ feats,   // (B, C, 256) fp32
    const float* __restrict__ depth,   // (B, 256)    fp32
    const float* __restrict__ cam,     // (3, 256)    fp32
    float* __restrict__ out)           // (B, C, 1024) fp32
{
    const int b = blockIdx.x;   // batch
    const int q = blockIdx.y;   // cell quarter 0..3
    const int t = threadIdx.x;  // 0..255

    __shared__ int s_y[NPTS];       // y voxel index per point
    __shared__ int s_next[NPTS];    // linked-list next per point
    __shared__ int s_besty[NCELL];  // max valid y per cell (-1 = unoccupied)
    __shared__ int s_head[NCELL];   // linked-list head per cell

    // init per-cell state
    for (int i = t; i < NCELL; i += 256) { s_besty[i] = -1; s_head[i] = -1; }
    __syncthreads();

    // ---- phase 1: voxelize the 256 points of this batch ----
    // pc = depth * cam_ray; pc.y += CAM_HEIGHT
    // Explicit round-to-nearest ops so the compiler cannot FMA-contract
    // (must match the numpy f32 reference at floor/valid boundaries).
    const float d  = depth[b * NPTS + t];
    const float cx = cam[0 * NPTS + t];
    const float cy = cam[1 * NPTS + t];
    const float cz = cam[2 * NPTS + t];

    const float px = __fmul_rn(d, cx);
    const float py = __fadd_rn(__fmul_rn(d, cy), CAMH);
    const float pz = __fmul_rn(d, cz);

    const int xi = (int)floorf(__fdiv_rn(px, CELLF)) + MAPS / 2;
    const int yi = (int)floorf(__fdiv_rn(py, CELLF));
    const int zi = (int)floorf(__fdiv_rn(pz, CELLF)) + MAPS;

    const bool valid = (xi >= 0) && (xi < MAPS) && (zi >= 0) && (zi < MAPS) && (yi < HMAXV);
    const int cell = zi * MAPS + xi;

    s_y[t] = yi;
    if (valid) {
        atomicMax(&s_besty[cell], yi);             // highest occupied y per cell
        s_next[t] = atomicExch(&s_head[cell], t);  // push point onto cell chain
    }
    __syncthreads();

    // ---- phase 2: emit this block's 256 cells x 128 channels ----
    const int cell2 = q * 256 + t;                 // consecutive cells -> coalesced stores
    const int by = s_besty[cell2];
    const int hd = s_head[cell2];
    const float* __restrict__ fb = feats + (size_t)b * NCHAN * NPTS;
    float* __restrict__ ob = out + (size_t)b * NCHAN * NCELL + cell2;

    if (by < 0) {
        #pragma unroll 4
        for (int c = 0; c < NCHAN; ++c)
            ob[(size_t)c * NCELL] = 0.0f;
    } else {
        for (int c = 0; c < NCHAN; ++c) {
            float sum = 0.0f;
            for (int p = hd; p >= 0; p = s_next[p]) {
                if (s_y[p] == by)
                    sum += fb[c * NPTS + p];
            }
            ob[(size_t)c * NCELL] = sum;
        }
    }
}

extern "C" void kernel_launch(void* const* d_in, const int* in_sizes, int n_in,
                              void* d_out, int out_size, void* d_ws, size_t ws_size,
                              hipStream_t stream) {
    const float* feats = (const float*)d_in[0];  // (64,128,16,16) fp32
    const float* depth = (const float*)d_in[1];  // (64,1,16,16)   fp32
    const float* cam   = (const float*)d_in[2];  // (3,256)        fp32
    float* out = (float*)d_out;                  // (64,128,32,32) fp32

    dim3 grid(NBATCH, 4);
    voxel_bev_kernel<<<grid, 256, 0, stream>>>(feats, depth, cam, out);
}

// Round 4
// 73.821 us; speedup vs baseline: 2.2191x; 2.2191x over previous
//
#include <hip/hip_runtime.h>

// ProjectWDepth: B=64, C=128, 256 pts/batch -> (64,128,32,32) fp32 BEV grid.
// Two-phase: build per-batch CSR of "highest-y" matched points (tiny), then
// a wide emit kernel that is pure coalesced streaming.
#define NBATCH   64
#define NCHAN    128
#define NPTS     256
#define MAPS     32
#define NCELL    (MAPS * MAPS)   // 1024
#define HMAXV    14
#define CELLF    0.1f
#define CAMH     1.72f
// ws layout per batch (ints): [0..1024] CSR offsets, [1088..1343] point list
#define WS_STRIDE 2048           // ints (8 KB) per batch -> 512 KB total

__global__ __launch_bounds__(256) void build_kernel(
    const float* __restrict__ depth,   // (B,256)
    const float* __restrict__ cam,     // (3,256)
    int* __restrict__ ws)
{
    const int b = blockIdx.x, t = threadIdx.x;
    __shared__ int s_besty[NCELL];
    __shared__ int s_cnt[NCELL];     // counts, then reused as per-cell offsets
    __shared__ int s_fill[NCELL];
    __shared__ int s_scan[256];

    #pragma unroll
    for (int k = 0; k < 4; ++k) {
        const int i = t * 4 + k;
        s_besty[i] = -1; s_cnt[i] = 0; s_fill[i] = 0;
    }
    __syncthreads();

    // voxelize point t of batch b (explicit _rn ops: no FMA contraction,
    // must match numpy f32 at floor/valid boundaries)
    const float d  = depth[b * NPTS + t];
    const float cx = cam[t], cy = cam[NPTS + t], cz = cam[2 * NPTS + t];
    const float px = __fmul_rn(d, cx);
    const float py = __fadd_rn(__fmul_rn(d, cy), CAMH);
    const float pz = __fmul_rn(d, cz);
    const int xi = (int)floorf(__fdiv_rn(px, CELLF)) + MAPS / 2;
    const int yi = (int)floorf(__fdiv_rn(py, CELLF));
    const int zi = (int)floorf(__fdiv_rn(pz, CELLF)) + MAPS;
    const bool valid = (xi >= 0) && (xi < MAPS) && (zi >= 0) && (zi < MAPS) && (yi < HMAXV);
    const int cell = valid ? (zi * MAPS + xi) : 0;

    if (valid) atomicMax(&s_besty[cell], yi);
    __syncthreads();
    const bool matched = valid && (yi == s_besty[cell]);
    if (matched) atomicAdd(&s_cnt[cell], 1);
    __syncthreads();

    // CSR offsets: per-thread partial over its 4 cells, then block scan
    const int c0 = t * 4;
    const int l0 = s_cnt[c0], l1 = s_cnt[c0 + 1], l2 = s_cnt[c0 + 2], l3 = s_cnt[c0 + 3];
    s_scan[t] = l0 + l1 + l2 + l3;
    __syncthreads();
    for (int dstep = 1; dstep < 256; dstep <<= 1) {   // inclusive Hillis-Steele
        const int v = (t >= dstep) ? s_scan[t - dstep] : 0;
        __syncthreads();
        s_scan[t] += v;
        __syncthreads();
    }
    const int base = (t > 0) ? s_scan[t - 1] : 0;
    const int o0 = base, o1 = base + l0, o2 = o1 + l1, o3 = o2 + l2;
    s_cnt[c0] = o0; s_cnt[c0 + 1] = o1; s_cnt[c0 + 2] = o2; s_cnt[c0 + 3] = o3;
    __syncthreads();

    int* wsb = ws + b * WS_STRIDE;
    ((int4*)wsb)[t] = make_int4(o0, o1, o2, o3);      // offs[0..1023]
    if (t == 255) wsb[NCELL] = s_scan[255];           // offs[1024] = total

    if (matched) {
        const int pos = atomicAdd(&s_fill[cell], 1);
        wsb[1088 + s_cnt[cell] + pos] = t;            // point list
    }
}

__global__ __launch_bounds__(256) void emit_kernel(
    const float* __restrict__ feats,   // (B,C,256)
    const int* __restrict__ ws,
    float* __restrict__ out)           // (B,C,1024)
{
    const int b = blockIdx.x, ct = blockIdx.y, t = threadIdx.x;
    __shared__ int   s_off[NCELL + 1];
    __shared__ int   s_pl[NPTS];
    __shared__ float s_f[4 * NPTS];    // 4 channels x 256 points

    const int* wsb = ws + b * WS_STRIDE;
    const int4 o4 = ((const int4*)wsb)[t];
    s_off[t * 4] = o4.x; s_off[t * 4 + 1] = o4.y;
    s_off[t * 4 + 2] = o4.z; s_off[t * 4 + 3] = o4.w;
    if (t == 0) s_off[NCELL] = wsb[NCELL];
    s_pl[t] = wsb[1088 + t];           // entries >= total are never read below

    const int c0 = ct * 4;
    const float* frow = feats + ((size_t)b * NCHAN + c0) * NPTS;
    ((float4*)s_f)[t] = ((const float4*)frow)[t];     // 4 KB coalesced stage
    __syncthreads();

    float* ob = out + ((size_t)b * NCHAN + c0) * NCELL;
    #pragma unroll
    for (int k = 0; k < 4; ++k) {
        const int cell = t + 256 * k;                 // consecutive threads -> coalesced
        const int s = s_off[cell], e = s_off[cell + 1];
        float a0 = 0.f, a1 = 0.f, a2 = 0.f, a3 = 0.f;
        for (int j = s; j < e; ++j) {
            const int p = s_pl[j];
            a0 += s_f[p];
            a1 += s_f[NPTS + p];
            a2 += s_f[2 * NPTS + p];
            a3 += s_f[3 * NPTS + p];
        }
        ob[cell]             = a0;
        ob[NCELL + cell]     = a1;
        ob[2 * NCELL + cell] = a2;
        ob[3 * NCELL + cell] = a3;
    }
}

extern "C" void kernel_launch(void* const* d_in, const int* in_sizes, int n_in,
                              void* d_out, int out_size, void* d_ws, size_t ws_size,
                              hipStream_t stream) {
    const float* feats = (const float*)d_in[0];  // (64,128,16,16) fp32
    const float* depth = (const float*)d_in[1];  // (64,1,16,16)   fp32
    const float* cam   = (const float*)d_in[2];  // (3,256)        fp32
    float* out = (float*)d_out;                  // (64,128,32,32) fp32
    int* ws = (int*)d_ws;                        // 512 KB used

    build_kernel<<<NBATCH, 256, 0, stream>>>(depth, cam, ws);
    emit_kernel<<<dim3(NBATCH, NCHAN / 4), 256, 0, stream>>>(feats, ws, out);
}

// Round 5
// 70.994 us; speedup vs baseline: 2.3074x; 1.0398x over previous
//
#include <hip/hip_runtime.h>

// ProjectWDepth: B=64, C=128, 256 pts/batch -> (64,128,32,32) fp32 BEV grid.
// Single fused kernel: each block = (batch, channel-quad). Rebuild the tiny
// per-batch voxelization in LDS (cheap, ~40 VALU), scatter matched features
// into a 4x1024 LDS tile via LDS float atomics, stream the tile out as
// coalesced float4 rows. No workspace, one launch.
#define NBATCH   64
#define NCHAN    128
#define NPTS     256
#define MAPS     32
#define NCELL    (MAPS * MAPS)   // 1024
#define HMAXV    14
#define CELLF    0.1f
#define CAMH     1.72f

__global__ __launch_bounds__(256) void fused_bev_kernel(
    const float* __restrict__ feats,   // (B, C, 256) fp32
    const float* __restrict__ depth,   // (B, 256)    fp32
    const float* __restrict__ cam,     // (3, 256)    fp32
    float* __restrict__ out)           // (B, C, 1024) fp32
{
    const int b  = blockIdx.x;   // batch
    const int cq = blockIdx.y;   // channel quad 0..31
    const int t  = threadIdx.x;  // 0..255

    __shared__ int   s_besty[NCELL];       // 4 KB
    __shared__ float s_tile[4][NCELL];     // 16 KB

    // init (stride-1 float4 / int: conflict-free)
    #pragma unroll
    for (int k = 0; k < 4; ++k) s_besty[t + 256 * k] = -1;
    #pragma unroll
    for (int k = 0; k < 4; ++k)
        ((float4*)&s_tile[k][0])[t] = make_float4(0.f, 0.f, 0.f, 0.f);

    // ---- voxelize point t of batch b ----
    // Explicit _rn ops: no FMA contraction; must match numpy f32 bit-for-bit
    // at floor/valid boundaries.
    const float d  = depth[b * NPTS + t];
    const float cx = cam[t], cy = cam[NPTS + t], cz = cam[2 * NPTS + t];

    // issue feature loads early (channel-quad rows, coalesced across t)
    const int c0 = cq * 4;
    const float* __restrict__ fb = feats + ((size_t)b * NCHAN + c0) * NPTS;
    const float f0 = fb[t];
    const float f1 = fb[NPTS + t];
    const float f2 = fb[2 * NPTS + t];
    const float f3 = fb[3 * NPTS + t];

    const float px = __fmul_rn(d, cx);
    const float py = __fadd_rn(__fmul_rn(d, cy), CAMH);
    const float pz = __fmul_rn(d, cz);
    const int xi = (int)floorf(__fdiv_rn(px, CELLF)) + MAPS / 2;
    const int yi = (int)floorf(__fdiv_rn(py, CELLF));
    const int zi = (int)floorf(__fdiv_rn(pz, CELLF)) + MAPS;
    const bool valid = (xi >= 0) && (xi < MAPS) && (zi >= 0) && (zi < MAPS) && (yi < HMAXV);
    const int cell = valid ? (zi * MAPS + xi) : 0;

    __syncthreads();                       // init visible
    if (valid) atomicMax(&s_besty[cell], yi);
    __syncthreads();

    // ---- scatter matched features into the LDS tile ----
    if (valid && yi == s_besty[cell]) {    // highest occupied y in this cell
        atomicAdd(&s_tile[0][cell], f0);
        atomicAdd(&s_tile[1][cell], f1);
        atomicAdd(&s_tile[2][cell], f2);
        atomicAdd(&s_tile[3][cell], f3);
    }
    __syncthreads();

    // ---- stream tile to global: 4 rows x 1024 cells, float4 coalesced ----
    float* __restrict__ ob = out + ((size_t)b * NCHAN + c0) * NCELL;
    #pragma unroll
    for (int k = 0; k < 4; ++k)
        ((float4*)(ob + (size_t)k * NCELL))[t] = ((float4*)&s_tile[k][0])[t];
}

extern "C" void kernel_launch(void* const* d_in, const int* in_sizes, int n_in,
                              void* d_out, int out_size, void* d_ws, size_t ws_size,
                              hipStream_t stream) {
    const float* feats = (const float*)d_in[0];  // (64,128,16,16) fp32
    const float* depth = (const float*)d_in[1];  // (64,1,16,16)   fp32
    const float* cam   = (const float*)d_in[2];  // (3,256)        fp32
    float* out = (float*)d_out;                  // (64,128,32,32) fp32

    fused_bev_kernel<<<dim3(NBATCH, NCHAN / 4), 256, 0, stream>>>(feats, depth, cam, out);
}